// Round 12
// baseline (84.030 us; speedup 1.0000x reference)
//
#include <hip/hip_runtime.h>
#include <hip/hip_bf16.h>
#include <stdint.h>

// Problem constants
#define B_ 16
#define C_ 256
#define H_ 64
#define W_ 64
#define WP 66                  // padded width: w' = w+1, border cols 0 and 65 zero
#define HP 66                  // padded height: h' = h+1, border rows 0 and 65 zero
#define ROWB (WP * C_)         // bytes per padded row of fp8 signs = 16896
#define STAGEB (3 * ROWB)      // 3 rows staged contiguously = 50688

typedef __attribute__((ext_vector_type(4))) float f32x4;
typedef __attribute__((ext_vector_type(4))) int int4v;
typedef __attribute__((ext_vector_type(8))) int int8v;

typedef const __attribute__((address_space(1))) uint32_t* gptr_t;
typedef __attribute__((address_space(3))) uint32_t* lptr_t;

__device__ __forceinline__ void gl_lds16(const void* g, void* l) {
  __builtin_amdgcn_global_load_lds((gptr_t)g, (lptr_t)l, 16, 0, 0);
}

// fp8 e4m3fn signs: +1 = 0x38, -1 = 0xB8, 0 = 0x00 (exact)
__device__ __forceinline__ uint8_t sgn8(float v) {
  return v > 0.f ? (uint8_t)0x38 : (v < 0.f ? (uint8_t)0xB8 : (uint8_t)0);
}

// ---------- kernel A: weight scale + fp8 signs, K=128 scaled-MFMA layout ----------
// wtb[t][ot][kh][mi][lane][32] ; lane's full 32B A-frag contiguous.
// o = ot*64 + mi*16 + (l&15), c = kh*128 + (l>>4)*32 + hf*16 + jj
__global__ void prep_w(const float* __restrict__ w, float* __restrict__ scale,
                       uint8_t* __restrict__ wtb) {
  int o = blockIdx.x, c = threadIdx.x;
  const float* wo = w + (size_t)o * 2304 + (size_t)c * 9;  // w[o][c][kh][kw]
  float v[9];
  float s = 0.f;
#pragma unroll
  for (int t = 0; t < 9; ++t) { v[t] = wo[t]; s += fabsf(v[t]); }
  __shared__ float red[256];
  red[c] = s;
  __syncthreads();
  for (int st = 128; st > 0; st >>= 1) {
    if (c < st) red[c] += red[c + st];
    __syncthreads();
  }
  if (c == 0) scale[o] = red[0] / 2304.0f;
  int ot = o >> 6, mi = (o >> 4) & 3, lm = o & 15;
  int kh = (c >> 7) & 1, lk2 = (c >> 5) & 3, hf = (c >> 4) & 1, jj = c & 15;
  int l = lk2 * 16 + lm;
#pragma unroll
  for (int t = 0; t < 9; ++t)
    wtb[(((((size_t)t * 4 + ot) * 2 + kh) * 4 + mi) * 64 + l) * 32 + hf * 16 + jj] =
        sgn8(v[t]);
}

// ---------- kernel B: binarize + transpose to swizzled padded fp8 layout ----------
// a_p row index = b*66 + (h+1); per row 66 pixel-blocks of 256B = 16 chunks of 16B,
// chunk = (c>>4)&15 (pure linear in c), stored chunk = chunk ^ (w' & 15).
__global__ void binarize(const float* __restrict__ x, const float* __restrict__ bias,
                         uint8_t* __restrict__ a_p) {
  int bh = blockIdx.x, b = bh >> 6, h = bh & 63, c0 = blockIdx.y * 64;
  int tid = threadIdx.x;
  __shared__ uint8_t lt[64][72];  // [w][ci]
#pragma unroll
  for (int p = 0; p < 4; ++p) {
    int ci = p * 16 + (tid >> 4), w4 = (tid & 15) * 4;
    f32x4 v = *(const f32x4*)(x + (((size_t)(b * C_ + c0 + ci) * H_ + h) * W_ + w4));
    float bb = bias[c0 + ci];
#pragma unroll
    for (int k = 0; k < 4; ++k) lt[w4 + k][ci] = sgn8(v[k] + bb);
  }
  __syncthreads();
  size_t rowbase = (size_t)(b * HP + h + 1) * ROWB;
#pragma unroll
  for (int p = 0; p < 4; ++p) {
    int w = p * 16 + (tid >> 4), cp = (tid & 15) * 4, c = c0 + cp;
    uint32_t val = (uint32_t)lt[w][cp] | ((uint32_t)lt[w][cp + 1] << 8) |
                   ((uint32_t)lt[w][cp + 2] << 16) | ((uint32_t)lt[w][cp + 3] << 24);
    int wp = w + 1;
    int pos = wp * 256 + ((((c >> 4) ^ wp) & 15) << 4) + (c & 15);
    *(uint32_t*)(a_p + rowbase + pos) = val;
  }
  // zero border columns of this row; for edge h, zero the padded border rows.
  if (blockIdx.y == 0) {
    if (tid < 64) *(uint32_t*)(a_p + rowbase + tid * 4) = 0;
    else if (tid < 128) *(uint32_t*)(a_p + rowbase + 65 * 256 + (tid - 64) * 4) = 0;
  }
  if (h == 0) {  // zero row h'=0 (quarter per y-block)
    uint32_t* zr = (uint32_t*)(a_p + (size_t)b * HP * ROWB) + blockIdx.y * 1056;
    for (int k = tid; k < 1056; k += 256) zr[k] = 0;
  } else if (h == 63) {  // zero row h'=65
    uint32_t* zr = (uint32_t*)(a_p + ((size_t)b * HP + 65) * ROWB) + blockIdx.y * 1056;
    for (int k = tid; k < 1056; k += 256) zr[k] = 0;
  }
}

// ---------- kernel C: binary conv via MX-scaled fp8 MFMA (K=128, 2x rate) ----------
// Round-10 delta: B-fragments ping-ponged one step ahead (bA/bB) like W, so
// ds_read latency hides under the previous 16-MFMA burst (round-9 MfmaUtil=30%
// with just-in-time bf loads). wtb re-laid so each lane's 32B frag is contiguous.
#define LOADW(dst, t, kh) {                                                       \
  const uint8_t* wb_ = wtb + ((((size_t)(t) * 4 + wv) * 2 + (kh)) * 4) * 2048 + l * 32; \
  _Pragma("unroll") for (int mi = 0; mi < 4; ++mi)                                \
      dst[mi] = *(const int8v*)(wb_ + mi * 2048); }

#define LOADB(dst, d, dxi, kh) {                                                  \
  int ch_ = (kh) * 8 + lk * 2;                                                    \
  _Pragma("unroll") for (int ni = 0; ni < 4; ++ni) {                              \
    int wp_ = ni * 16 + lm + (dxi);                                               \
    const uint8_t* bb_ = smem + (d) * ROWB + wp_ * 256;                           \
    int4v b0_ = *(const int4v*)(bb_ + ((ch_ ^ wp_) & 15) * 16);                   \
    int4v b1_ = *(const int4v*)(bb_ + (((ch_ + 1) ^ wp_) & 15) * 16);             \
    dst[ni] = __builtin_shufflevector(b0_, b1_, 0, 1, 2, 3, 4, 5, 6, 7); } }

#define MFMA_BURST(wreg, breg)                                                    \
  __builtin_amdgcn_s_setprio(1);                                                  \
  _Pragma("unroll") for (int mi = 0; mi < 4; ++mi)                                \
    _Pragma("unroll") for (int ni = 0; ni < 4; ++ni)                              \
      acc[mi][ni] = __builtin_amdgcn_mfma_scale_f32_16x16x128_f8f6f4(             \
          wreg[mi], breg[ni], acc[mi][ni], 0, 0, 0, 127, 0, 127);                 \
  __builtin_amdgcn_s_setprio(0);

__global__ __launch_bounds__(256, 2) void bconv(
    const uint8_t* __restrict__ a_p, const uint8_t* __restrict__ wtb,
    const float* __restrict__ scale, const float* __restrict__ x,
    const float* __restrict__ pb0, const float* __restrict__ alpha,
    const float* __restrict__ pb1, float* __restrict__ out) {
  __shared__ __attribute__((aligned(16))) uint8_t smem[STAGEB];
  // XCD-aware bijective swizzle: 1024 blocks, 8 XCDs, 128 contiguous per XCD
  int bh = (blockIdx.x & 7) * 128 + (blockIdx.x >> 3);
  int b = bh >> 6, h = bh & 63;
  int tid = threadIdx.x, l = tid & 63, wv = tid >> 6;
  int lm = l & 15, lk = l >> 4;
  int wm = wv * 64;

  // stage 3 contiguous padded rows (h', h'+1, h'+2) = input rows h-1,h,h+1
  const uint8_t* src = a_p + (size_t)(b * HP + h) * ROWB;
#pragma unroll
  for (int it = 0; it < 12; ++it)
    gl_lds16(src + (size_t)(it * 256 + tid) * 16, smem + it * 4096 + wv * 1024);
  if (tid < 96) gl_lds16(src + 49152 + (size_t)tid * 16, smem + 49152 + wv * 1024);

  f32x4 acc[4][4];
#pragma unroll
  for (int i = 0; i < 4; ++i)
#pragma unroll
    for (int j = 0; j < 4; ++j) acc[i][j] = (f32x4){0.f, 0.f, 0.f, 0.f};

  asm volatile("s_waitcnt vmcnt(0)" ::: "memory");
  __syncthreads();

  int8v wA[4], wB[4], bA[4], bB[4];
  LOADB(bA, 0, 0, 0)
  LOADW(wA, 0, 0)
#pragma unroll 1
  for (int t = 0; t < 9; ++t) {      // tap loop NOT unrolled: fences code motion
    int d = t / 3, dxi = t - d * 3;
    // step kh=0: prefetch (t,1) into wB/bB, compute wA/bA
    LOADB(bB, d, dxi, 1)
    LOADW(wB, t, 1)
    MFMA_BURST(wA, bA)
    // step kh=1: prefetch (t+1,0) into wA/bA, compute wB/bB
    if (t < 8) {
      int t1 = t + 1, d1 = t1 / 3, dxi1 = t1 - d1 * 3;
      LOADB(bA, d1, dxi1, 0)
      LOADW(wA, t1, 0)
    }
    MFMA_BURST(wB, bB)
  }

  // epilogue: conv*scale + pb0 -> PReLU -> + pb1 + x (residual)
  size_t xb = (size_t)b * C_ * H_ * W_ + (size_t)h * W_;
#pragma unroll
  for (int mi = 0; mi < 4; ++mi) {
#pragma unroll
    for (int j = 0; j < 4; ++j) {
      int o = wm + mi * 16 + lk * 4 + j;  // C/D row = (lane>>4)*4 + reg
      float sc = scale[o], b0 = pb0[o], al = alpha[o], b1 = pb1[o];
      size_t rowo = xb + (size_t)o * (H_ * W_);
#pragma unroll
      for (int ni = 0; ni < 4; ++ni) {
        int wcol = ni * 16 + lm;          // C/D col = lane&15
        float v = acc[mi][ni][j] * sc + b0;
        v = v >= 0.f ? v : al * v;
        v = v + b1 + x[rowo + wcol];
        out[rowo + wcol] = v;
      }
    }
  }
}

extern "C" void kernel_launch(void* const* d_in, const int* in_sizes, int n_in,
                              void* d_out, int out_size, void* d_ws, size_t ws_size,
                              hipStream_t stream) {
  const float* x     = (const float*)d_in[0];
  const float* m0b   = (const float*)d_in[1];
  const float* w     = (const float*)d_in[2];
  const float* pb0   = (const float*)d_in[3];
  const float* alpha = (const float*)d_in[4];
  const float* pb1   = (const float*)d_in[5];
  float* out = (float*)d_out;

  // ws: [0,4KB) scale | [4096, +589824) wtb fp8 | a_p padded 16*66*16896 = 17.8MB
  float* scale = (float*)d_ws;
  uint8_t* wtb = (uint8_t*)d_ws + 4096;
  uint8_t* a_p = (uint8_t*)d_ws + 4096 + (size_t)9 * 4 * 2 * 4 * 2048;

  hipLaunchKernelGGL(prep_w, dim3(C_), dim3(256), 0, stream, w, scale, wtb);
  hipLaunchKernelGGL(binarize, dim3(B_ * H_, C_ / 64), dim3(256), 0, stream, x, m0b, a_p);
  hipLaunchKernelGGL(bconv, dim3(B_ * H_), dim3(256), 0, stream,
                     a_p, wtb, scale, x, pb0, alpha, pb1, out);
}

// Round 14
// 64.353 us; speedup vs baseline: 1.3058x; 1.3058x over previous
//
#include <hip/hip_runtime.h>
#include <hip/hip_bf16.h>
#include <stdint.h>

// Problem constants
#define B_ 16
#define C_ 256
#define H_ 64
#define W_ 64
#define WP 66                  // padded width: w' = w+1, border cols 0 and 65 zero
#define HP 66                  // padded height: h' = h+1, border rows 0 and 65 zero
#define ROWB (WP * C_)         // bytes per padded row of fp8 signs = 16896
#define STAGEB (3 * ROWB)      // 3 rows staged contiguously = 50688

typedef __attribute__((ext_vector_type(4))) float f32x4;
typedef __attribute__((ext_vector_type(4))) int int4v;
typedef __attribute__((ext_vector_type(8))) int int8v;

typedef const __attribute__((address_space(1))) uint32_t* gptr_t;
typedef __attribute__((address_space(3))) uint32_t* lptr_t;

__device__ __forceinline__ void gl_lds16(const void* g, void* l) {
  __builtin_amdgcn_global_load_lds((gptr_t)g, (lptr_t)l, 16, 0, 0);
}

// fp8 e4m3fn signs: +1 = 0x38, -1 = 0xB8, 0 = 0x00 (exact)
__device__ __forceinline__ uint8_t sgn8(float v) {
  return v > 0.f ? (uint8_t)0x38 : (v < 0.f ? (uint8_t)0xB8 : (uint8_t)0);
}

// ---------- kernel A: weight scale + fp8 signs, K=128 scaled-MFMA layout ----------
// wtb[t][ot][kh][mi][lane][32] ; lane's full 32B A-frag contiguous.
// o = ot*64 + mi*16 + (l&15), c = kh*128 + (l>>4)*32 + hf*16 + jj
__global__ void prep_w(const float* __restrict__ w, float* __restrict__ scale,
                       uint8_t* __restrict__ wtb) {
  int o = blockIdx.x, c = threadIdx.x;
  const float* wo = w + (size_t)o * 2304 + (size_t)c * 9;  // w[o][c][kh][kw]
  float v[9];
  float s = 0.f;
#pragma unroll
  for (int t = 0; t < 9; ++t) { v[t] = wo[t]; s += fabsf(v[t]); }
  __shared__ float red[256];
  red[c] = s;
  __syncthreads();
  for (int st = 128; st > 0; st >>= 1) {
    if (c < st) red[c] += red[c + st];
    __syncthreads();
  }
  if (c == 0) scale[o] = red[0] / 2304.0f;
  int ot = o >> 6, mi = (o >> 4) & 3, lm = o & 15;
  int kh = (c >> 7) & 1, lk2 = (c >> 5) & 3, hf = (c >> 4) & 1, jj = c & 15;
  int l = lk2 * 16 + lm;
#pragma unroll
  for (int t = 0; t < 9; ++t)
    wtb[(((((size_t)t * 4 + ot) * 2 + kh) * 4 + mi) * 64 + l) * 32 + hf * 16 + jj] =
        sgn8(v[t]);
}

// ---------- kernel B: binarize + transpose to swizzled padded fp8 layout ----------
// a_p row index = b*66 + (h+1); per row 66 pixel-blocks of 256B = 16 chunks of 16B,
// chunk = (c>>4)&15 (pure linear in c), stored chunk = chunk ^ (w' & 15).
__global__ void binarize(const float* __restrict__ x, const float* __restrict__ bias,
                         uint8_t* __restrict__ a_p) {
  int bh = blockIdx.x, b = bh >> 6, h = bh & 63, c0 = blockIdx.y * 64;
  int tid = threadIdx.x;
  __shared__ uint8_t lt[64][72];  // [w][ci]
#pragma unroll
  for (int p = 0; p < 4; ++p) {
    int ci = p * 16 + (tid >> 4), w4 = (tid & 15) * 4;
    f32x4 v = *(const f32x4*)(x + (((size_t)(b * C_ + c0 + ci) * H_ + h) * W_ + w4));
    float bb = bias[c0 + ci];
#pragma unroll
    for (int k = 0; k < 4; ++k) lt[w4 + k][ci] = sgn8(v[k] + bb);
  }
  __syncthreads();
  size_t rowbase = (size_t)(b * HP + h + 1) * ROWB;
#pragma unroll
  for (int p = 0; p < 4; ++p) {
    int w = p * 16 + (tid >> 4), cp = (tid & 15) * 4, c = c0 + cp;
    uint32_t val = (uint32_t)lt[w][cp] | ((uint32_t)lt[w][cp + 1] << 8) |
                   ((uint32_t)lt[w][cp + 2] << 16) | ((uint32_t)lt[w][cp + 3] << 24);
    int wp = w + 1;
    int pos = wp * 256 + ((((c >> 4) ^ wp) & 15) << 4) + (c & 15);
    *(uint32_t*)(a_p + rowbase + pos) = val;
  }
  // zero border columns of this row; for edge h, zero the padded border rows.
  if (blockIdx.y == 0) {
    if (tid < 64) *(uint32_t*)(a_p + rowbase + tid * 4) = 0;
    else if (tid < 128) *(uint32_t*)(a_p + rowbase + 65 * 256 + (tid - 64) * 4) = 0;
  }
  if (h == 0) {  // zero row h'=0 (quarter per y-block)
    uint32_t* zr = (uint32_t*)(a_p + (size_t)b * HP * ROWB) + blockIdx.y * 1056;
    for (int k = tid; k < 1056; k += 256) zr[k] = 0;
  } else if (h == 63) {  // zero row h'=65
    uint32_t* zr = (uint32_t*)(a_p + ((size_t)b * HP + 65) * ROWB) + blockIdx.y * 1056;
    for (int k = tid; k < 1056; k += 256) zr[k] = 0;
  }
}

// ---------- kernel C: binary conv via MX-scaled fp8 MFMA (K=128, 2x rate) ----------
// Round-9 pipeline (best measured: wA/wB ping-pong, bf JIT) + round-12's
// contiguous 32B W-layout so LOADW is 4 bases + adjacent b128 pairs (no
// shuffles, less addr VALU). B double-buffering reverted (round-12 spill).
#define LOADW(dst, t, kh) {                                                       \
  const uint8_t* wb_ = wtb + ((((size_t)(t) * 4 + wv) * 2 + (kh)) * 4) * 2048 + l * 32; \
  _Pragma("unroll") for (int mi = 0; mi < 4; ++mi)                                \
      dst[mi] = *(const int8v*)(wb_ + mi * 2048); }

#define LOADB(dst, d, dxi, kh) {                                                  \
  int ch_ = (kh) * 8 + lk * 2;                                                    \
  _Pragma("unroll") for (int ni = 0; ni < 4; ++ni) {                              \
    int wp_ = ni * 16 + lm + (dxi);                                               \
    const uint8_t* bb_ = smem + (d) * ROWB + wp_ * 256;                           \
    int4v b0_ = *(const int4v*)(bb_ + ((ch_ ^ wp_) & 15) * 16);                   \
    int4v b1_ = *(const int4v*)(bb_ + (((ch_ + 1) ^ wp_) & 15) * 16);             \
    dst[ni] = __builtin_shufflevector(b0_, b1_, 0, 1, 2, 3, 4, 5, 6, 7); } }

#define MFMA_BURST(wreg)                                                          \
  __builtin_amdgcn_s_setprio(1);                                                  \
  _Pragma("unroll") for (int mi = 0; mi < 4; ++mi)                                \
    _Pragma("unroll") for (int ni = 0; ni < 4; ++ni)                              \
      acc[mi][ni] = __builtin_amdgcn_mfma_scale_f32_16x16x128_f8f6f4(             \
          wreg[mi], bf[ni], acc[mi][ni], 0, 0, 0, 127, 0, 127);                   \
  __builtin_amdgcn_s_setprio(0);

__global__ __launch_bounds__(256, 2) void bconv(
    const uint8_t* __restrict__ a_p, const uint8_t* __restrict__ wtb,
    const float* __restrict__ scale, const float* __restrict__ x,
    const float* __restrict__ pb0, const float* __restrict__ alpha,
    const float* __restrict__ pb1, float* __restrict__ out) {
  __shared__ __attribute__((aligned(16))) uint8_t smem[STAGEB];
  // XCD-aware bijective swizzle: 1024 blocks, 8 XCDs, 128 contiguous per XCD
  int bh = (blockIdx.x & 7) * 128 + (blockIdx.x >> 3);
  int b = bh >> 6, h = bh & 63;
  int tid = threadIdx.x, l = tid & 63, wv = tid >> 6;
  int lm = l & 15, lk = l >> 4;
  int wm = wv * 64;

  // stage 3 contiguous padded rows (h', h'+1, h'+2) = input rows h-1,h,h+1
  const uint8_t* src = a_p + (size_t)(b * HP + h) * ROWB;
#pragma unroll
  for (int it = 0; it < 12; ++it)
    gl_lds16(src + (size_t)(it * 256 + tid) * 16, smem + it * 4096 + wv * 1024);
  if (tid < 96) gl_lds16(src + 49152 + (size_t)tid * 16, smem + 49152 + wv * 1024);

  f32x4 acc[4][4];
#pragma unroll
  for (int i = 0; i < 4; ++i)
#pragma unroll
    for (int j = 0; j < 4; ++j) acc[i][j] = (f32x4){0.f, 0.f, 0.f, 0.f};

  asm volatile("s_waitcnt vmcnt(0)" ::: "memory");
  __syncthreads();

  int8v wA[4], wB[4], bf[4];
  LOADW(wA, 0, 0)
#pragma unroll 1
  for (int t = 0; t < 9; ++t) {      // tap loop NOT unrolled: fences code motion
    int d = t / 3, dxi = t - d * 3;
    // step kh=0: compute with wA, prefetch (t,1) into wB
    LOADW(wB, t, 1)
    LOADB(bf, d, dxi, 0)
    MFMA_BURST(wA)
    // step kh=1: compute with wB, prefetch (t+1,0) into wA
    if (t < 8) { LOADW(wA, t + 1, 0) }
    LOADB(bf, d, dxi, 1)
    MFMA_BURST(wB)
  }

  // epilogue: conv*scale + pb0 -> PReLU -> + pb1 + x (residual)
  size_t xb = (size_t)b * C_ * H_ * W_ + (size_t)h * W_;
#pragma unroll
  for (int mi = 0; mi < 4; ++mi) {
#pragma unroll
    for (int j = 0; j < 4; ++j) {
      int o = wm + mi * 16 + lk * 4 + j;  // C/D row = (lane>>4)*4 + reg
      float sc = scale[o], b0 = pb0[o], al = alpha[o], b1 = pb1[o];
      size_t rowo = xb + (size_t)o * (H_ * W_);
#pragma unroll
      for (int ni = 0; ni < 4; ++ni) {
        int wcol = ni * 16 + lm;          // C/D col = lane&15
        float v = acc[mi][ni][j] * sc + b0;
        v = v >= 0.f ? v : al * v;
        v = v + b1 + x[rowo + wcol];
        out[rowo + wcol] = v;
      }
    }
  }
}

extern "C" void kernel_launch(void* const* d_in, const int* in_sizes, int n_in,
                              void* d_out, int out_size, void* d_ws, size_t ws_size,
                              hipStream_t stream) {
  const float* x     = (const float*)d_in[0];
  const float* m0b   = (const float*)d_in[1];
  const float* w     = (const float*)d_in[2];
  const float* pb0   = (const float*)d_in[3];
  const float* alpha = (const float*)d_in[4];
  const float* pb1   = (const float*)d_in[5];
  float* out = (float*)d_out;

  // ws: [0,4KB) scale | [4096, +589824) wtb fp8 | a_p padded 16*66*16896 = 17.8MB
  float* scale = (float*)d_ws;
  uint8_t* wtb = (uint8_t*)d_ws + 4096;
  uint8_t* a_p = (uint8_t*)d_ws + 4096 + (size_t)9 * 4 * 2 * 4 * 2048;

  hipLaunchKernelGGL(prep_w, dim3(C_), dim3(256), 0, stream, w, scale, wtb);
  hipLaunchKernelGGL(binarize, dim3(B_ * H_, C_ / 64), dim3(256), 0, stream, x, m0b, a_p);
  hipLaunchKernelGGL(bconv, dim3(B_ * H_), dim3(256), 0, stream,
                     a_p, wtb, scale, x, pb0, alpha, pb1, out);
}

// Round 17
// 63.550 us; speedup vs baseline: 1.3223x; 1.0126x over previous
//
#include <hip/hip_runtime.h>
#include <hip/hip_bf16.h>
#include <stdint.h>

// Problem constants
#define B_ 16
#define C_ 256
#define H_ 64
#define W_ 64
#define WP 66                  // padded width: w' = w+1, border cols 0 and 65 zero
#define HP 66                  // padded height: h' = h+1, border rows 0 and 65 zero
#define ROWB (WP * C_)         // bytes per padded row of fp8 signs = 16896
#define STAGEB (3 * ROWB)      // 3 rows staged contiguously = 50688

typedef __attribute__((ext_vector_type(4))) float f32x4;
typedef __attribute__((ext_vector_type(4))) int int4v;
typedef __attribute__((ext_vector_type(8))) int int8v;

typedef const __attribute__((address_space(1))) uint32_t* gptr_t;
typedef __attribute__((address_space(3))) uint32_t* lptr_t;

__device__ __forceinline__ void gl_lds16(const void* g, void* l) {
  __builtin_amdgcn_global_load_lds((gptr_t)g, (lptr_t)l, 16, 0, 0);
}

// fp8 e4m3fn signs: +1 = 0x38, -1 = 0xB8, 0 = 0x00 (exact)
__device__ __forceinline__ uint8_t sgn8(float v) {
  return v > 0.f ? (uint8_t)0x38 : (v < 0.f ? (uint8_t)0xB8 : (uint8_t)0);
}

// ---------- kernel A: weight scale + fp8 signs, K=128 scaled-MFMA layout ----------
// wtb[t][ot][kh][mi][lane][32] ; lane's full 32B A-frag contiguous.
// o = ot*64 + mi*16 + (l&15), c = kh*128 + (l>>4)*32 + hf*16 + jj
__global__ void prep_w(const float* __restrict__ w, float* __restrict__ scale,
                       uint8_t* __restrict__ wtb) {
  int o = blockIdx.x, c = threadIdx.x;
  const float* wo = w + (size_t)o * 2304 + (size_t)c * 9;  // w[o][c][kh][kw]
  float v[9];
  float s = 0.f;
#pragma unroll
  for (int t = 0; t < 9; ++t) { v[t] = wo[t]; s += fabsf(v[t]); }
  __shared__ float red[256];
  red[c] = s;
  __syncthreads();
  for (int st = 128; st > 0; st >>= 1) {
    if (c < st) red[c] += red[c + st];
    __syncthreads();
  }
  if (c == 0) scale[o] = red[0] / 2304.0f;
  int ot = o >> 6, mi = (o >> 4) & 3, lm = o & 15;
  int kh = (c >> 7) & 1, lk2 = (c >> 5) & 3, hf = (c >> 4) & 1, jj = c & 15;
  int l = lk2 * 16 + lm;
#pragma unroll
  for (int t = 0; t < 9; ++t)
    wtb[(((((size_t)t * 4 + ot) * 2 + kh) * 4 + mi) * 64 + l) * 32 + hf * 16 + jj] =
        sgn8(v[t]);
}

// ---------- kernel B: binarize + transpose to swizzled padded fp8 layout ----------
// a_p row index = b*66 + (h+1); per row 66 pixel-blocks of 256B = 16 chunks of 16B,
// chunk = (c>>4)&15 (pure linear in c), stored chunk = chunk ^ (w' & 15).
__global__ void binarize(const float* __restrict__ x, const float* __restrict__ bias,
                         uint8_t* __restrict__ a_p) {
  int bh = blockIdx.x, b = bh >> 6, h = bh & 63, c0 = blockIdx.y * 64;
  int tid = threadIdx.x;
  __shared__ uint8_t lt[64][72];  // [w][ci]
#pragma unroll
  for (int p = 0; p < 4; ++p) {
    int ci = p * 16 + (tid >> 4), w4 = (tid & 15) * 4;
    f32x4 v = *(const f32x4*)(x + (((size_t)(b * C_ + c0 + ci) * H_ + h) * W_ + w4));
    float bb = bias[c0 + ci];
#pragma unroll
    for (int k = 0; k < 4; ++k) lt[w4 + k][ci] = sgn8(v[k] + bb);
  }
  __syncthreads();
  size_t rowbase = (size_t)(b * HP + h + 1) * ROWB;
#pragma unroll
  for (int p = 0; p < 4; ++p) {
    int w = p * 16 + (tid >> 4), cp = (tid & 15) * 4, c = c0 + cp;
    uint32_t val = (uint32_t)lt[w][cp] | ((uint32_t)lt[w][cp + 1] << 8) |
                   ((uint32_t)lt[w][cp + 2] << 16) | ((uint32_t)lt[w][cp + 3] << 24);
    int wp = w + 1;
    int pos = wp * 256 + ((((c >> 4) ^ wp) & 15) << 4) + (c & 15);
    *(uint32_t*)(a_p + rowbase + pos) = val;
  }
  // zero border columns of this row; for edge h, zero the padded border rows.
  if (blockIdx.y == 0) {
    if (tid < 64) *(uint32_t*)(a_p + rowbase + tid * 4) = 0;
    else if (tid < 128) *(uint32_t*)(a_p + rowbase + 65 * 256 + (tid - 64) * 4) = 0;
  }
  if (h == 0) {  // zero row h'=0 (quarter per y-block)
    uint32_t* zr = (uint32_t*)(a_p + (size_t)b * HP * ROWB) + blockIdx.y * 1056;
    for (int k = tid; k < 1056; k += 256) zr[k] = 0;
  } else if (h == 63) {  // zero row h'=65
    uint32_t* zr = (uint32_t*)(a_p + ((size_t)b * HP + 65) * ROWB) + blockIdx.y * 1056;
    for (int k = tid; k < 1056; k += 256) zr[k] = 0;
  }
}

// ---------- kernel C: binary conv via MX-scaled fp8 MFMA (K=128, 2x rate) ----------
// Round-15: JIT-load W and B each step (no ping-pong) to shrink live regs
// ~150 < 170 cap -> __launch_bounds__(256,3): 3 blocks/CU = 12 waves/CU.
// History shows MfmaUtil ~ linear in resident waves (12w: 46-55%, 8w: 20-30%);
// 3 waves/SIMD cover the JIT load latency with their own bursts.
#define LOADW(dst, t, kh) {                                                       \
  const uint8_t* wb_ = wtb + ((((size_t)(t) * 4 + wv) * 2 + (kh)) * 4) * 2048 + l * 32; \
  _Pragma("unroll") for (int mi = 0; mi < 4; ++mi)                                \
      dst[mi] = *(const int8v*)(wb_ + mi * 2048); }

#define LOADB(dst, d, dxi, kh) {                                                  \
  int ch_ = (kh) * 8 + lk * 2;                                                    \
  _Pragma("unroll") for (int ni = 0; ni < 4; ++ni) {                              \
    int wp_ = ni * 16 + lm + (dxi);                                               \
    const uint8_t* bb_ = smem + (d) * ROWB + wp_ * 256;                           \
    int4v b0_ = *(const int4v*)(bb_ + ((ch_ ^ wp_) & 15) * 16);                   \
    int4v b1_ = *(const int4v*)(bb_ + (((ch_ + 1) ^ wp_) & 15) * 16);             \
    dst[ni] = __builtin_shufflevector(b0_, b1_, 0, 1, 2, 3, 4, 5, 6, 7); } }

#define MFMA_BURST(wreg)                                                          \
  __builtin_amdgcn_s_setprio(1);                                                  \
  _Pragma("unroll") for (int mi = 0; mi < 4; ++mi)                                \
    _Pragma("unroll") for (int ni = 0; ni < 4; ++ni)                              \
      acc[mi][ni] = __builtin_amdgcn_mfma_scale_f32_16x16x128_f8f6f4(             \
          wreg[mi], bf[ni], acc[mi][ni], 0, 0, 0, 127, 0, 127);                   \
  __builtin_amdgcn_s_setprio(0);

__global__ __launch_bounds__(256, 3) void bconv(
    const uint8_t* __restrict__ a_p, const uint8_t* __restrict__ wtb,
    const float* __restrict__ scale, const float* __restrict__ x,
    const float* __restrict__ pb0, const float* __restrict__ alpha,
    const float* __restrict__ pb1, float* __restrict__ out) {
  __shared__ __attribute__((aligned(16))) uint8_t smem[STAGEB];
  // XCD-aware bijective swizzle: 1024 blocks, 8 XCDs, 128 contiguous per XCD
  int bh = (blockIdx.x & 7) * 128 + (blockIdx.x >> 3);
  int b = bh >> 6, h = bh & 63;
  int tid = threadIdx.x, l = tid & 63, wv = tid >> 6;
  int lm = l & 15, lk = l >> 4;
  int wm = wv * 64;

  // stage 3 contiguous padded rows (h', h'+1, h'+2) = input rows h-1,h,h+1
  const uint8_t* src = a_p + (size_t)(b * HP + h) * ROWB;
#pragma unroll
  for (int it = 0; it < 12; ++it)
    gl_lds16(src + (size_t)(it * 256 + tid) * 16, smem + it * 4096 + wv * 1024);
  if (tid < 96) gl_lds16(src + 49152 + (size_t)tid * 16, smem + 49152 + wv * 1024);

  f32x4 acc[4][4];
#pragma unroll
  for (int i = 0; i < 4; ++i)
#pragma unroll
    for (int j = 0; j < 4; ++j) acc[i][j] = (f32x4){0.f, 0.f, 0.f, 0.f};

  asm volatile("s_waitcnt vmcnt(0)" ::: "memory");
  __syncthreads();

  int8v wf[4], bf[4];
#pragma unroll 1
  for (int t = 0; t < 9; ++t) {      // tap loop NOT unrolled: fences code motion
    int d = t / 3, dxi = t - d * 3;
#pragma unroll 1
    for (int kh = 0; kh < 2; ++kh) { // kh loop also fenced: keeps live set small
      LOADW(wf, t, kh)               // issue global W first (longest latency)
      LOADB(bf, d, dxi, kh)          // then LDS B; waits overlap
      MFMA_BURST(wf)
    }
  }

  // epilogue: conv*scale + pb0 -> PReLU -> + pb1 + x (residual)
  size_t xb = (size_t)b * C_ * H_ * W_ + (size_t)h * W_;
#pragma unroll
  for (int mi = 0; mi < 4; ++mi) {
#pragma unroll
    for (int j = 0; j < 4; ++j) {
      int o = wm + mi * 16 + lk * 4 + j;  // C/D row = (lane>>4)*4 + reg
      float sc = scale[o], b0 = pb0[o], al = alpha[o], b1 = pb1[o];
      size_t rowo = xb + (size_t)o * (H_ * W_);
#pragma unroll
      for (int ni = 0; ni < 4; ++ni) {
        int wcol = ni * 16 + lm;          // C/D col = lane&15
        float v = acc[mi][ni][j] * sc + b0;
        v = v >= 0.f ? v : al * v;
        v = v + b1 + x[rowo + wcol];
        out[rowo + wcol] = v;
      }
    }
  }
}

extern "C" void kernel_launch(void* const* d_in, const int* in_sizes, int n_in,
                              void* d_out, int out_size, void* d_ws, size_t ws_size,
                              hipStream_t stream) {
  const float* x     = (const float*)d_in[0];
  const float* m0b   = (const float*)d_in[1];
  const float* w     = (const float*)d_in[2];
  const float* pb0   = (const float*)d_in[3];
  const float* alpha = (const float*)d_in[4];
  const float* pb1   = (const float*)d_in[5];
  float* out = (float*)d_out;

  // ws: [0,4KB) scale | [4096, +589824) wtb fp8 | a_p padded 16*66*16896 = 17.8MB
  float* scale = (float*)d_ws;
  uint8_t* wtb = (uint8_t*)d_ws + 4096;
  uint8_t* a_p = (uint8_t*)d_ws + 4096 + (size_t)9 * 4 * 2 * 4 * 2048;

  hipLaunchKernelGGL(prep_w, dim3(C_), dim3(256), 0, stream, w, scale, wtb);
  hipLaunchKernelGGL(binarize, dim3(B_ * H_, C_ / 64), dim3(256), 0, stream, x, m0b, a_p);
  hipLaunchKernelGGL(bconv, dim3(B_ * H_), dim3(256), 0, stream,
                     a_p, wtb, scale, x, pb0, alpha, pb1, out);
}

// Round 18
// 54.356 us; speedup vs baseline: 1.5459x; 1.1691x over previous
//
#include <hip/hip_runtime.h>
#include <hip/hip_bf16.h>
#include <stdint.h>

// Problem constants
#define B_ 16
#define C_ 256
#define H_ 64
#define W_ 64
#define WP 66                   // padded width: w' = w+1, border cols 0 and 65 zero
#define HP 66                   // padded height: h' = h+1, border rows 0 and 65 zero
#define ROWB (WP * 128)         // bytes per padded row of fp4 signs = 8448
#define STAGEB (3 * ROWB + 32)  // 3 rows staged + over-read pad = 25376

typedef __attribute__((ext_vector_type(4))) float f32x4;
typedef __attribute__((ext_vector_type(8))) int int8v;

typedef const __attribute__((address_space(1))) uint32_t* gptr_t;
typedef __attribute__((address_space(3))) uint32_t* lptr_t;

__device__ __forceinline__ void gl_lds16(const void* g, void* l) {
  __builtin_amdgcn_global_load_lds((gptr_t)g, (lptr_t)l, 16, 0, 0);
}

// fp4 e2m1 signs: +1 = 0x2, -1 = 0xA, 0 = 0x0 (exact)
__device__ __forceinline__ uint8_t sgn4(float v) {
  return v > 0.f ? (uint8_t)0x2 : (v < 0.f ? (uint8_t)0xA : (uint8_t)0);
}

// ---------- kernel A: weight scale + fp4 signs, K=128 scaled-MFMA layout ----------
// wtb[t][ot][kh][mi][lane][16B] ; lane's 32-element (16B) fp4 A-frag.
// o = ot*64 + mi*16 + (l&15), c = kh*128 + (l>>4)*32 + j (nibble j of 16B)
__global__ void prep_w(const float* __restrict__ w, float* __restrict__ scale,
                       uint8_t* __restrict__ wtb) {
  int o = blockIdx.x, c = threadIdx.x;
  const float* wo = w + (size_t)o * 2304 + (size_t)c * 9;  // w[o][c][kh][kw]
  float v[9];
  float s = 0.f;
#pragma unroll
  for (int t = 0; t < 9; ++t) { v[t] = wo[t]; s += fabsf(v[t]); }
  __shared__ float red[256];
  __shared__ uint8_t sg[9][256];
  red[c] = s;
#pragma unroll
  for (int t = 0; t < 9; ++t) sg[t][c] = sgn4(v[t]);
  __syncthreads();
  for (int st = 128; st > 0; st >>= 1) {
    if (c < st) red[c] += red[c + st];
    __syncthreads();
  }
  if (c == 0) scale[o] = red[0] / 2304.0f;
  if (c < 128) {               // thread c packs channels 2c, 2c+1 into one byte
    int k = c;
    int ot = o >> 6, mi = (o >> 4) & 3, lm = o & 15;
    int kh = k >> 6, lk = (k >> 4) & 3, jb = k & 15;
    int l = lk * 16 + lm;
#pragma unroll
    for (int t = 0; t < 9; ++t) {
      uint8_t byte = (uint8_t)(sg[t][2 * k] | (sg[t][2 * k + 1] << 4));
      wtb[((((size_t)t * 4 + ot) * 2 + kh) * 4 + mi) * 1024 + l * 16 + jb] = byte;
    }
  }
}

// ---------- kernel B: binarize + transpose to swizzled padded fp4 layout ----------
// a_p row index = b*66 + (h+1); per row 66 pixel-blocks of 128B = 8 chunks of 16B,
// chunk = (c>>5) (linear in c), stored chunk = chunk ^ (w' & 7). Nibble c&1.
__global__ void binarize(const float* __restrict__ x, const float* __restrict__ bias,
                         uint8_t* __restrict__ a_p) {
  int bh = blockIdx.x, b = bh >> 6, h = bh & 63, c0 = blockIdx.y * 64;
  int tid = threadIdx.x;
  __shared__ uint8_t lt[64][72];  // [w][ci], sgn4 value in low nibble
#pragma unroll
  for (int p = 0; p < 4; ++p) {
    int ci = p * 16 + (tid >> 4), w4 = (tid & 15) * 4;
    f32x4 v = *(const f32x4*)(x + (((size_t)(b * C_ + c0 + ci) * H_ + h) * W_ + w4));
    float bb = bias[c0 + ci];
#pragma unroll
    for (int k = 0; k < 4; ++k) lt[w4 + k][ci] = sgn4(v[k] + bb);
  }
  __syncthreads();
  size_t rowbase = (size_t)(b * HP + h + 1) * ROWB;
#pragma unroll
  for (int r = 0; r < 2; ++r) {
    int u = r * 256 + tid;             // 0..511 ; this y-block: 64 px x 8 u32
    int w = u >> 3, q = u & 7;         // q-th u32 (8 channels) of pixel w
    uint32_t val = 0;
#pragma unroll
    for (int e = 0; e < 8; ++e)
      val |= (uint32_t)(lt[w][q * 8 + e] & 15) << (4 * e);
    int wp = w + 1;
    int ch = (c0 + q * 8) >> 5;
    int pos = wp * 128 + (((ch ^ wp) & 7) << 4) + (q & 3) * 4;
    *(uint32_t*)(a_p + rowbase + pos) = val;
  }
  // zero border pixel blocks (128B each); for edge h, zero the padded border rows.
  if (blockIdx.y == 0) {
    if (tid < 32) *(uint32_t*)(a_p + rowbase + tid * 4) = 0;
    else if (tid < 64) *(uint32_t*)(a_p + rowbase + 65 * 128 + (tid - 32) * 4) = 0;
  }
  if (h == 0) {  // zero row h'=0 (quarter per y-block)
    uint32_t* zr = (uint32_t*)(a_p + (size_t)b * HP * ROWB) + blockIdx.y * 528;
    for (int k = tid; k < 528; k += 256) zr[k] = 0;
  } else if (h == 63) {  // zero row h'=65
    uint32_t* zr = (uint32_t*)(a_p + ((size_t)b * HP + 65) * ROWB) + blockIdx.y * 528;
    for (int k = tid; k < 528; k += 256) zr[k] = 0;
  }
}

// ---------- kernel C: binary conv via MX-scaled fp4 MFMA (K=128, ~1.55x fp8 rate) ----------
// Round-17 structure (JIT W+B, 3 blocks/CU); round-18 delta: fp4 (cbsz=blgp=4).
// Operands are 16B real data loaded as 32B int8v (over-read; fp4 ignores upper
// 4 regs). Halves loads, LDS, a_p traffic; pipe 34.5->22.3 cyc/MFMA.
#define LOADW(dst, t, kh) {                                                       \
  const uint8_t* wb_ = wtb + ((((size_t)(t) * 4 + wv) * 2 + (kh)) * 4) * 1024 + l * 16; \
  _Pragma("unroll") for (int mi = 0; mi < 4; ++mi)                                \
      dst[mi] = *(const int8v*)(wb_ + mi * 1024); }

#define LOADB(dst, d, dxi, kh) {                                                  \
  int ch_ = (kh) * 4 + lk;                                                        \
  _Pragma("unroll") for (int ni = 0; ni < 4; ++ni) {                              \
    int wp_ = ni * 16 + lm + (dxi);                                               \
    dst[ni] = *(const int8v*)(smem + (d) * ROWB + wp_ * 128 +                     \
                              (((ch_ ^ wp_) & 7) << 4)); } }

#define MFMA_BURST(wreg)                                                          \
  __builtin_amdgcn_s_setprio(1);                                                  \
  _Pragma("unroll") for (int mi = 0; mi < 4; ++mi)                                \
    _Pragma("unroll") for (int ni = 0; ni < 4; ++ni)                              \
      acc[mi][ni] = __builtin_amdgcn_mfma_scale_f32_16x16x128_f8f6f4(             \
          wreg[mi], bf[ni], acc[mi][ni], 4, 4, 0, 127, 0, 127);                   \
  __builtin_amdgcn_s_setprio(0);

__global__ __launch_bounds__(256, 3) void bconv(
    const uint8_t* __restrict__ a_p, const uint8_t* __restrict__ wtb,
    const float* __restrict__ scale, const float* __restrict__ x,
    const float* __restrict__ pb0, const float* __restrict__ alpha,
    const float* __restrict__ pb1, float* __restrict__ out) {
  __shared__ __attribute__((aligned(16))) uint8_t smem[STAGEB];
  // XCD-aware bijective swizzle: 1024 blocks, 8 XCDs, 128 contiguous per XCD
  int bh = (blockIdx.x & 7) * 128 + (blockIdx.x >> 3);
  int b = bh >> 6, h = bh & 63;
  int tid = threadIdx.x, l = tid & 63, wv = tid >> 6;
  int lm = l & 15, lk = l >> 4;
  int wm = wv * 64;

  // stage 3 contiguous padded rows (h', h'+1, h'+2) = input rows h-1,h,h+1
  const uint8_t* src = a_p + (size_t)(b * HP + h) * ROWB;
#pragma unroll
  for (int it = 0; it < 6; ++it)
    gl_lds16(src + (size_t)(it * 256 + tid) * 16, smem + it * 4096 + wv * 1024);
  if (tid < 48) gl_lds16(src + 24576 + (size_t)tid * 16, smem + 24576);

  f32x4 acc[4][4];
#pragma unroll
  for (int i = 0; i < 4; ++i)
#pragma unroll
    for (int j = 0; j < 4; ++j) acc[i][j] = (f32x4){0.f, 0.f, 0.f, 0.f};

  asm volatile("s_waitcnt vmcnt(0)" ::: "memory");
  __syncthreads();

  int8v wf[4], bf[4];
#pragma unroll 1
  for (int t = 0; t < 9; ++t) {      // tap loop NOT unrolled: fences code motion
    int d = t / 3, dxi = t - d * 3;
#pragma unroll 1
    for (int kh = 0; kh < 2; ++kh) { // kh loop also fenced: keeps live set small
      LOADW(wf, t, kh)               // issue global W first (longest latency)
      LOADB(bf, d, dxi, kh)          // then LDS B; waits overlap
      MFMA_BURST(wf)
    }
  }

  // epilogue: conv*scale + pb0 -> PReLU -> + pb1 + x (residual)
  size_t xb = (size_t)b * C_ * H_ * W_ + (size_t)h * W_;
#pragma unroll
  for (int mi = 0; mi < 4; ++mi) {
#pragma unroll
    for (int j = 0; j < 4; ++j) {
      int o = wm + mi * 16 + lk * 4 + j;  // C/D row = (lane>>4)*4 + reg
      float sc = scale[o], b0 = pb0[o], al = alpha[o], b1 = pb1[o];
      size_t rowo = xb + (size_t)o * (H_ * W_);
#pragma unroll
      for (int ni = 0; ni < 4; ++ni) {
        int wcol = ni * 16 + lm;          // C/D col = lane&15
        float v = acc[mi][ni][j] * sc + b0;
        v = v >= 0.f ? v : al * v;
        v = v + b1 + x[rowo + wcol];
        out[rowo + wcol] = v;
      }
    }
  }
}

extern "C" void kernel_launch(void* const* d_in, const int* in_sizes, int n_in,
                              void* d_out, int out_size, void* d_ws, size_t ws_size,
                              hipStream_t stream) {
  const float* x     = (const float*)d_in[0];
  const float* m0b   = (const float*)d_in[1];
  const float* w     = (const float*)d_in[2];
  const float* pb0   = (const float*)d_in[3];
  const float* alpha = (const float*)d_in[4];
  const float* pb1   = (const float*)d_in[5];
  float* out = (float*)d_out;

  // ws: [0,4KB) scale | [4096, +294912+pad) wtb fp4 | a_p padded 16*66*8448 = 8.9MB
  float* scale = (float*)d_ws;
  uint8_t* wtb = (uint8_t*)d_ws + 4096;
  uint8_t* a_p = (uint8_t*)d_ws + 4096 + (size_t)9 * 4 * 2 * 4 * 1024 + 1024;

  hipLaunchKernelGGL(prep_w, dim3(C_), dim3(256), 0, stream, w, scale, wtb);
  hipLaunchKernelGGL(binarize, dim3(B_ * H_, C_ / 64), dim3(256), 0, stream, x, m0b, a_p);
  hipLaunchKernelGGL(bconv, dim3(B_ * H_), dim3(256), 0, stream,
                     a_p, wtb, scale, x, pb0, alpha, pb1, out);
}

// Round 19
// 53.915 us; speedup vs baseline: 1.5586x; 1.0082x over previous
//
#include <hip/hip_runtime.h>
#include <hip/hip_bf16.h>
#include <stdint.h>

// Problem constants
#define B_ 16
#define C_ 256
#define H_ 64
#define W_ 64
#define WP 66                   // padded width: w' = w+1, border cols 0 and 65 zero
#define HP 66                   // padded height: h' = h+1, border rows 0 and 65 zero
#define ROWB (WP * 128)         // bytes per padded row of fp4 signs = 8448
#define STAGEB (3 * ROWB + 32)  // 3 rows staged + pad = 25376

typedef __attribute__((ext_vector_type(4))) float f32x4;
typedef __attribute__((ext_vector_type(4))) int int4v;
typedef __attribute__((ext_vector_type(8))) int int8v;

typedef const __attribute__((address_space(1))) uint32_t* gptr_t;
typedef __attribute__((address_space(3))) uint32_t* lptr_t;

__device__ __forceinline__ void gl_lds16(const void* g, void* l) {
  __builtin_amdgcn_global_load_lds((gptr_t)g, (lptr_t)l, 16, 0, 0);
}

// fp4 e2m1 signs: +1 = 0x2, -1 = 0xA, 0 = 0x0 (exact)
__device__ __forceinline__ uint8_t sgn4(float v) {
  return v > 0.f ? (uint8_t)0x2 : (v < 0.f ? (uint8_t)0xA : (uint8_t)0);
}

// fp4 uses only the low 4 regs of the 8-reg f8f6f4 operand; upper 4 undef.
#define EXT8(v4) __builtin_shufflevector((v4), (v4), 0, 1, 2, 3, -1, -1, -1, -1)

// ---------- kernel A: weight scale + fp4 signs, K=128 scaled-MFMA layout ----------
// wtb[t][ot][kh][mi][lane][16B] ; lane's 32-element (16B) fp4 A-frag.
// o = ot*64 + mi*16 + (l&15), c = kh*128 + (l>>4)*32 + j (nibble j of 16B)
__global__ void prep_w(const float* __restrict__ w, float* __restrict__ scale,
                       uint8_t* __restrict__ wtb) {
  int o = blockIdx.x, c = threadIdx.x;
  const float* wo = w + (size_t)o * 2304 + (size_t)c * 9;  // w[o][c][kh][kw]
  float v[9];
  float s = 0.f;
#pragma unroll
  for (int t = 0; t < 9; ++t) { v[t] = wo[t]; s += fabsf(v[t]); }
  __shared__ float red[256];
  __shared__ uint8_t sg[9][256];
  red[c] = s;
#pragma unroll
  for (int t = 0; t < 9; ++t) sg[t][c] = sgn4(v[t]);
  __syncthreads();
  for (int st = 128; st > 0; st >>= 1) {
    if (c < st) red[c] += red[c + st];
    __syncthreads();
  }
  if (c == 0) scale[o] = red[0] / 2304.0f;
  if (c < 128) {               // thread c packs channels 2c, 2c+1 into one byte
    int k = c;
    int ot = o >> 6, mi = (o >> 4) & 3, lm = o & 15;
    int kh = k >> 6, lk = (k >> 4) & 3, jb = k & 15;
    int l = lk * 16 + lm;
#pragma unroll
    for (int t = 0; t < 9; ++t) {
      uint8_t byte = (uint8_t)(sg[t][2 * k] | (sg[t][2 * k + 1] << 4));
      wtb[((((size_t)t * 4 + ot) * 2 + kh) * 4 + mi) * 1024 + l * 16 + jb] = byte;
    }
  }
}

// ---------- kernel B: binarize + transpose to swizzled padded fp4 layout ----------
// a_p row index = b*66 + (h+1); per row 66 pixel-blocks of 128B = 8 chunks of 16B,
// chunk = (c>>5) (linear in c), stored chunk = chunk ^ (w' & 7). Nibble c&1.
__global__ void binarize(const float* __restrict__ x, const float* __restrict__ bias,
                         uint8_t* __restrict__ a_p) {
  int bh = blockIdx.x, b = bh >> 6, h = bh & 63, c0 = blockIdx.y * 64;
  int tid = threadIdx.x;
  __shared__ uint8_t lt[64][72];  // [w][ci], sgn4 value in low nibble
#pragma unroll
  for (int p = 0; p < 4; ++p) {
    int ci = p * 16 + (tid >> 4), w4 = (tid & 15) * 4;
    f32x4 v = *(const f32x4*)(x + (((size_t)(b * C_ + c0 + ci) * H_ + h) * W_ + w4));
    float bb = bias[c0 + ci];
#pragma unroll
    for (int k = 0; k < 4; ++k) lt[w4 + k][ci] = sgn4(v[k] + bb);
  }
  __syncthreads();
  size_t rowbase = (size_t)(b * HP + h + 1) * ROWB;
#pragma unroll
  for (int r = 0; r < 2; ++r) {
    int u = r * 256 + tid;             // 0..511 ; this y-block: 64 px x 8 u32
    int w = u >> 3, q = u & 7;         // q-th u32 (8 channels) of pixel w
    uint32_t val = 0;
#pragma unroll
    for (int e = 0; e < 8; ++e)
      val |= (uint32_t)(lt[w][q * 8 + e] & 15) << (4 * e);
    int wp = w + 1;
    int ch = (c0 + q * 8) >> 5;
    int pos = wp * 128 + (((ch ^ wp) & 7) << 4) + (q & 3) * 4;
    *(uint32_t*)(a_p + rowbase + pos) = val;
  }
  // zero border pixel blocks (128B each); for edge h, zero the padded border rows.
  if (blockIdx.y == 0) {
    if (tid < 32) *(uint32_t*)(a_p + rowbase + tid * 4) = 0;
    else if (tid < 64) *(uint32_t*)(a_p + rowbase + 65 * 128 + (tid - 32) * 4) = 0;
  }
  if (h == 0) {  // zero row h'=0 (quarter per y-block)
    uint32_t* zr = (uint32_t*)(a_p + (size_t)b * HP * ROWB) + blockIdx.y * 528;
    for (int k = tid; k < 528; k += 256) zr[k] = 0;
  } else if (h == 63) {  // zero row h'=65
    uint32_t* zr = (uint32_t*)(a_p + ((size_t)b * HP + 65) * ROWB) + blockIdx.y * 528;
    for (int k = tid; k < 528; k += 256) zr[k] = 0;
  }
}

// ---------- kernel C: binary conv, MX-fp4 MFMA, int4v frags + W ping-pong ----------
// Round-19: operands loaded as int4v (16B exact; fp4 reads only low 4 regs,
// upper 4 undef-extended at the MFMA). Frag regs 96->48, enabling round-9's
// W ping-pong under the 170-reg cap at 3 blocks/CU: the JIT W-load L2 latency
// (the serial-chain long pole blocking wave overlap, r9/r17 MfmaUtil=30%) is
// prefetched one full step ahead; remaining chain is the ~150-cyc LDS B read.
#define LOADW(dst, t, kh) {                                                       \
  const uint8_t* wb_ = wtb + ((((size_t)(t) * 4 + wv) * 2 + (kh)) * 4) * 1024 + l * 16; \
  _Pragma("unroll") for (int mi = 0; mi < 4; ++mi)                                \
      dst[mi] = *(const int4v*)(wb_ + mi * 1024); }

#define LOADB(dst, d, dxi, kh) {                                                  \
  int ch_ = (kh) * 4 + lk;                                                        \
  _Pragma("unroll") for (int ni = 0; ni < 4; ++ni) {                              \
    int wp_ = ni * 16 + lm + (dxi);                                               \
    dst[ni] = *(const int4v*)(smem + (d) * ROWB + wp_ * 128 +                     \
                              (((ch_ ^ wp_) & 7) << 4)); } }

#define MFMA_BURST(wreg)                                                          \
  __builtin_amdgcn_s_setprio(1);                                                  \
  _Pragma("unroll") for (int mi = 0; mi < 4; ++mi)                                \
    _Pragma("unroll") for (int ni = 0; ni < 4; ++ni)                              \
      acc[mi][ni] = __builtin_amdgcn_mfma_scale_f32_16x16x128_f8f6f4(             \
          EXT8(wreg[mi]), EXT8(bf[ni]), acc[mi][ni], 4, 4, 0, 127, 0, 127);       \
  __builtin_amdgcn_s_setprio(0);

__global__ __launch_bounds__(256, 3) void bconv(
    const uint8_t* __restrict__ a_p, const uint8_t* __restrict__ wtb,
    const float* __restrict__ scale, const float* __restrict__ x,
    const float* __restrict__ pb0, const float* __restrict__ alpha,
    const float* __restrict__ pb1, float* __restrict__ out) {
  __shared__ __attribute__((aligned(16))) uint8_t smem[STAGEB];
  // XCD-aware bijective swizzle: 1024 blocks, 8 XCDs, 128 contiguous per XCD
  int bh = (blockIdx.x & 7) * 128 + (blockIdx.x >> 3);
  int b = bh >> 6, h = bh & 63;
  int tid = threadIdx.x, l = tid & 63, wv = tid >> 6;
  int lm = l & 15, lk = l >> 4;
  int wm = wv * 64;

  // stage 3 contiguous padded rows (h', h'+1, h'+2) = input rows h-1,h,h+1
  const uint8_t* src = a_p + (size_t)(b * HP + h) * ROWB;
#pragma unroll
  for (int it = 0; it < 6; ++it)
    gl_lds16(src + (size_t)(it * 256 + tid) * 16, smem + it * 4096 + wv * 1024);
  if (tid < 48) gl_lds16(src + 24576 + (size_t)tid * 16, smem + 24576);

  f32x4 acc[4][4];
#pragma unroll
  for (int i = 0; i < 4; ++i)
#pragma unroll
    for (int j = 0; j < 4; ++j) acc[i][j] = (f32x4){0.f, 0.f, 0.f, 0.f};

  asm volatile("s_waitcnt vmcnt(0)" ::: "memory");
  __syncthreads();

  int4v wA[4], wB[4], bf[4];
  LOADW(wA, 0, 0)
#pragma unroll 1
  for (int t = 0; t < 9; ++t) {      // tap loop NOT unrolled: fences code motion
    int d = t / 3, dxi = t - d * 3;
    // step kh=0: prefetch (t,1) into wB, B JIT, burst with wA
    LOADW(wB, t, 1)
    LOADB(bf, d, dxi, 0)
    MFMA_BURST(wA)
    // step kh=1: prefetch (t+1,0) into wA, B JIT, burst with wB
    if (t < 8) { LOADW(wA, t + 1, 0) }
    LOADB(bf, d, dxi, 1)
    MFMA_BURST(wB)
  }

  // epilogue: conv*scale + pb0 -> PReLU -> + pb1 + x (residual)
  size_t xb = (size_t)b * C_ * H_ * W_ + (size_t)h * W_;
#pragma unroll
  for (int mi = 0; mi < 4; ++mi) {
#pragma unroll
    for (int j = 0; j < 4; ++j) {
      int o = wm + mi * 16 + lk * 4 + j;  // C/D row = (lane>>4)*4 + reg
      float sc = scale[o], b0 = pb0[o], al = alpha[o], b1 = pb1[o];
      size_t rowo = xb + (size_t)o * (H_ * W_);
#pragma unroll
      for (int ni = 0; ni < 4; ++ni) {
        int wcol = ni * 16 + lm;          // C/D col = lane&15
        float v = acc[mi][ni][j] * sc + b0;
        v = v >= 0.f ? v : al * v;
        v = v + b1 + x[rowo + wcol];
        out[rowo + wcol] = v;
      }
    }
  }
}

extern "C" void kernel_launch(void* const* d_in, const int* in_sizes, int n_in,
                              void* d_out, int out_size, void* d_ws, size_t ws_size,
                              hipStream_t stream) {
  const float* x     = (const float*)d_in[0];
  const float* m0b   = (const float*)d_in[1];
  const float* w     = (const float*)d_in[2];
  const float* pb0   = (const float*)d_in[3];
  const float* alpha = (const float*)d_in[4];
  const float* pb1   = (const float*)d_in[5];
  float* out = (float*)d_out;

  // ws: [0,4KB) scale | [4096, +294912+pad) wtb fp4 | a_p padded 16*66*8448 = 8.9MB
  float* scale = (float*)d_ws;
  uint8_t* wtb = (uint8_t*)d_ws + 4096;
  uint8_t* a_p = (uint8_t*)d_ws + 4096 + (size_t)9 * 4 * 2 * 4 * 1024 + 1024;

  hipLaunchKernelGGL(prep_w, dim3(C_), dim3(256), 0, stream, w, scale, wtb);
  hipLaunchKernelGGL(binarize, dim3(B_ * H_, C_ / 64), dim3(256), 0, stream, x, m0b, a_p);
  hipLaunchKernelGGL(bconv, dim3(B_ * H_), dim3(256), 0, stream,
                     a_p, wtb, scale, x, pb0, alpha, pb1, out);
}